// Round 5
// baseline (176.166 us; speedup 1.0000x reference)
//
#include <hip/hip_runtime.h>
#include <math.h>

// MutualInformationLoss on MI355X — round 13.
// Round-12 post-mortem: LDS pipe is OP-bound (bytes -59%/ops +33% -> +1.1us).
// Dirty-row zeroing reverted; K1 restored to round-11 best (107.2us) form:
// PBLK=432, vf4 loads, full b128 zeroing (op-minimal), 29696B LDS -> 5 blk/CU.
// This round attacks the ~20us downstream pipeline (K2+K3+launch gaps):
//   Dataflow-triggered inline tails, no extra launches:
//   - per-group ticket gcnt[108]: the 16th K1 block of a 16-row group runs
//     that group's fp64 reduction inline (overlaps remaining K1 work);
//   - second ticket gcnt[108+1]: last reducer runs the MI finalize.
//   Cross-block partial[] now crosses XCDs IN-kernel: stores/loads are
//   device-scope atomics (round-9 proved atomic-mediated transfer works;
//   plain stores were only safe across the old kernel boundary).
//   Counters zeroed by a 17KB memsetAsync (cheap vs 2 launches + gaps).

#define NBINS   23
#define NCELLS  529
#define NBATCH  4
#define NVOX    884736
#define PBLK    432               // K1 blocks per batch: 432 * 2048 = 884736
#define RPB     16                // partial rows per reduce group
#define RBLK    (PBLK / RPB)      // 27 groups per batch
#define NGRP    (RBLK * NBATCH)   // 108 groups total
#define RS      72                // image row stride in halves (144 B)
#define IMGB    (24 * RS * 2)     // 3456 B per image (rows 0..23)
#define WREG    (2 * IMGB)        // 6912 B per wave (A + B images)
#define SMEMB   (4 * WREG + 2048) // 29696 B: guard covers row 24..31 overreads

typedef float    vf4  __attribute__((ext_vector_type(4)));
typedef _Float16 h8   __attribute__((ext_vector_type(8)));
typedef float    f16v __attribute__((ext_vector_type(16)));

#define G1 0.13533528f        // exp(-2)
#define G2 3.3546263e-4f      // exp(-8)
#define G3 1.5229979e-8f      // exp(-18)

// 7-bin window at rows i0..i0+6 via factored Gaussian (2 exp + 1 rcp):
//   w(t) = W0 * R^t * G(t), W0=exp(-968 v^2), R=exp(88 v), v = x - c_mid
__device__ __forceinline__ float window7(float x, int& i0, float* w)
{
    x = fminf(fmaxf(x, 0.0f), 1.0f);
    int ka = (int)floorf(fmaf(x, 22.0f, 0.5f));
    i0 = min(max(ka - 3, 0), 16);
    float v  = fmaf((float)(i0 + 3), -(1.0f / 22.0f), x);
    float W0 = __expf(-968.0f * v * v);
    float R  = __expf(88.0f * v);
    float Ri = __builtin_amdgcn_rcpf(R);
    float R2 = R * R,   R3 = R2 * R;
    float R2i = Ri * Ri, R3i = R2i * Ri;
    w[0] = W0 * (R3i * G3);
    w[1] = W0 * (R2i * G2);
    w[2] = W0 * (Ri  * G1);
    w[3] = W0;
    w[4] = W0 * (R   * G1);
    w[5] = W0 * (R2  * G2);
    w[6] = W0 * (R3  * G3);
    return ((w[0] + w[6]) + (w[1] + w[5])) + ((w[2] + w[4]) + w[3]);
}

// ------ fused: Parzen + MFMA histogram + ticket-triggered reduce/finalize ------
__global__ __launch_bounds__(256, 5)
void mi_mfma(const float* __restrict__ pred,
             const float* __restrict__ targ,
             float* __restrict__ partial,      // [NBATCH*PBLK][NCELLS]
             double* __restrict__ pab64,       // pre-zeroed (memset)
             int* __restrict__ gcnt,           // [NGRP+1], pre-zeroed
             float* __restrict__ out)
{
    __shared__ __align__(16) char smem[SMEMB];
    __shared__ int s_task;

    const int p    = blockIdx.x;
    const int b    = blockIdx.y;
    const int wv   = threadIdx.x >> 6;
    const int lane = threadIdx.x & 63;
    const int m    = lane & 31;               // bin row for fragment reads
    const int h    = lane >> 5;               // k-half selector

    char* wbase = smem + wv * WREG;
    _Float16* Aimg = (_Float16*)wbase;
    _Float16* Bimg = (_Float16*)(wbase + IMGB);

    const size_t base = (size_t)b * NVOX + (size_t)p * 2048 + (size_t)wv * 512
                      + (size_t)lane * 8;
    const vf4* __restrict__ px4 = (const vf4*)(pred + base);
    const vf4* __restrict__ py4 = (const vf4*)(targ + base);
    vf4 xa = px4[0], xb = px4[1], ya = py4[0], yb = py4[1];
    float xs[8] = {xa.x, xa.y, xa.z, xa.w, xb.x, xb.y, xb.z, xb.w};
    float ys[8] = {ya.x, ya.y, ya.z, ya.w, yb.x, yb.y, yb.z, yb.w};

    f16v acc = {};

    #pragma unroll
    for (int c = 0; c < 8; ++c) {
        // zero rows 0..23 of BOTH images in one contiguous 6912 B span.
        // Rows 24..31 never written; reads of them only pollute C rows/cols
        // >= 23, which are never consumed (validated round 9).
        vf4 z = {0.f, 0.f, 0.f, 0.f};
        #pragma unroll
        for (int it = 0; it < 6; ++it)
            *(vf4*)(wbase + (it * 64 + lane) * 16) = z;
        if (lane < 48)
            *(vf4*)(wbase + (384 + lane) * 16) = z;

        int ia, ja;
        float wa[7], wb[7];
        float sa = window7(xs[c], ia, wa);
        float sb = window7(ys[c], ja, wb);
        float inv = __builtin_amdgcn_rcpf(sa * sb);   // fold both norms onto A

        #pragma unroll
        for (int t = 0; t < 7; ++t) {
            Aimg[(ia + t) * RS + lane] = (_Float16)(wa[t] * inv);  // RNE cvt
            Bimg[(ja + t) * RS + lane] = (_Float16)wb[t];
        }

        // 4 k-steps of 32x32x16 (K=16 voxels each)
        #pragma unroll
        for (int s = 0; s < 4; ++s) {
            h8 Af = *(const h8*)(Aimg + m * RS + 16 * s + 8 * h);
            h8 Bf = *(const h8*)(Bimg + m * RS + 16 * s + 8 * h);
            acc = __builtin_amdgcn_mfma_f32_32x32x16_f16(Af, Bf, acc, 0, 0, 0);
        }
    }

    // epilogue: C layout col=lane&31, row=(reg&3)+8*(reg>>2)+4*h (m74/m101)
    float* tile = (float*)wbase;               // reuse wave region
    #pragma unroll
    for (int r = 0; r < 16; ++r) {
        int row = (r & 3) + 8 * (r >> 2) + 4 * h;
        tile[row * 33 + m] = acc[r];
    }
    __syncthreads();
    for (int c = threadIdx.x; c < NCELLS; c += 256) {
        int i = c / NBINS, j = c % NBINS;
        float s = 0.0f;
        #pragma unroll
        for (int w = 0; w < 4; ++w)
            s += ((const float*)(smem + w * WREG))[i * 33 + j];
        // device-scope store: crosses XCDs in-kernel (read by reduce tail)
        __hip_atomic_store(&partial[((size_t)(b * PBLK + p)) * NCELLS + c], s,
                           __ATOMIC_RELAXED, __HIP_MEMORY_SCOPE_AGENT);
    }

    // ---- group ticket: 16th finisher of each 16-row group reduces it ----
    __syncthreads();                           // all partial stores drained
    if (threadIdx.x == 0) {
        __threadfence();                       // release our stores
        const int grp = b * RBLK + p / RPB;
        int old = __hip_atomic_fetch_add(&gcnt[grp], 1, __ATOMIC_ACQ_REL,
                                         __HIP_MEMORY_SCOPE_AGENT);
        s_task = (old == RPB - 1) ? grp : -1;
    }
    __syncthreads();
    if (s_task < 0) return;

    {   // fp64 reduction of one 16-row group (ex-K2 body)
        const int grp = s_task;
        const int rb  = grp / RBLK;
        const int g   = grp % RBLK;
        const int t   = threadIdx.x;
        const float* __restrict__ src =
            partial + ((size_t)rb * PBLK + (size_t)g * RPB) * NCELLS;

        double a0 = 0.0, a1 = 0.0, a2 = 0.0;
        #pragma unroll
        for (int pr = 0; pr < RPB; ++pr) {
            const float* __restrict__ row = src + (size_t)pr * NCELLS;
            a0 += (double)__hip_atomic_load(&row[t], __ATOMIC_RELAXED,
                                            __HIP_MEMORY_SCOPE_AGENT);
            a1 += (double)__hip_atomic_load(&row[256 + t], __ATOMIC_RELAXED,
                                            __HIP_MEMORY_SCOPE_AGENT);
            if (t < NCELLS - 512)
                a2 += (double)__hip_atomic_load(&row[512 + t], __ATOMIC_RELAXED,
                                                __HIP_MEMORY_SCOPE_AGENT);
        }
        atomicAdd(&pab64[rb * NCELLS + t],       a0);   // 27-way: cheap
        atomicAdd(&pab64[rb * NCELLS + 256 + t], a1);
        if (t < NCELLS - 512) atomicAdd(&pab64[rb * NCELLS + 512 + t], a2);
    }

    // ---- final ticket: last reducer computes MI (ex-K3 body) ----
    __syncthreads();                           // our pab64 atomics drained
    if (threadIdx.x == 0) {
        __threadfence();
        int old = __hip_atomic_fetch_add(&gcnt[NGRP], 1, __ATOMIC_ACQ_REL,
                                         __HIP_MEMORY_SCOPE_AGENT);
        s_task = (old == NGRP - 1) ? 1 : -1;
    }
    __syncthreads();
    if (s_task < 0) return;

    {   // marginals + MI in fp64; atomic loads for cross-XCD coherence
        double* s_pab = (double*)smem;             // 4232 B
        double* s_pa  = (double*)(smem + 4240);
        double* s_pb  = (double*)(smem + 4432);
        double* s_red = (double*)(smem + 4624);
        const int t = threadIdx.x;

        double total = 0.0;
        for (int bb = 0; bb < NBATCH; ++bb) {
            for (int c = t; c < NCELLS; c += 256)
                s_pab[c] = __hip_atomic_load(&pab64[bb * NCELLS + c],
                                             __ATOMIC_RELAXED,
                                             __HIP_MEMORY_SCOPE_AGENT)
                           * (1.0 / (double)NVOX);
            __syncthreads();
            if (t < NBINS) {
                double r = 0.0, cl = 0.0;
                for (int j = 0; j < NBINS; ++j) {
                    r  += s_pab[t * NBINS + j];
                    cl += s_pab[j * NBINS + t];
                }
                s_pa[t] = r; s_pb[t] = cl;
            }
            __syncthreads();
            double tt = 0.0;
            for (int c = t; c < NCELLS; c += 256) {
                double pv   = s_pab[c];
                double papb = s_pa[c / NBINS] * s_pb[c % NBINS];
                tt += pv * log((pv + 1e-7) / (papb + 1e-7) + 1e-7);
            }
            #pragma unroll
            for (int off = 32; off > 0; off >>= 1)
                tt += __shfl_down(tt, off, 64);
            if ((t & 63) == 0) s_red[t >> 6] = tt;
            __syncthreads();
            if (t == 0) total += s_red[0] + s_red[1] + s_red[2] + s_red[3];
            __syncthreads();
        }
        if (t == 0) out[0] = (float)(-total * 0.25);
    }
}

extern "C" void kernel_launch(void* const* d_in, const int* in_sizes, int n_in,
                              void* d_out, int out_size, void* d_ws, size_t ws_size,
                              hipStream_t stream)
{
    const float* pred = (const float*)d_in[0];
    const float* targ = (const float*)d_in[1];
    float* out = (float*)d_out;
    char* ws = (char*)d_ws;

    // layout: [pab64: 2116 f64 = 16928 B][gcnt: 109 ints][pad to 32768]
    //         [partial: NBATCH*PBLK*NCELLS f32 = 3.66 MB]
    double* pab64   = (double*)ws;
    int*    gcnt    = (int*)(ws + 16928);
    float*  partial = (float*)(ws + 32768);

    (void)hipMemsetAsync(ws, 0, 17408, stream);
    mi_mfma<<<dim3(PBLK, NBATCH), 256, 0, stream>>>(pred, targ, partial,
                                                    pab64, gcnt, out);
}

// Round 8
// 114.761 us; speedup vs baseline: 1.5351x; 1.5351x over previous
//
#include <hip/hip_runtime.h>
#include <math.h>

// MutualInformationLoss on MI355X — round 16.
// Rounds 14/15 failed with IDENTICAL absmax 0.243 -> deterministic semantic
// error, not a race. Root cause: wrong model of ds_read_b64_tr_b16. True
// semantics (per guide T10's required [*/4][*/16][4][16] subtiling + m156):
// per 16-lane group, each lane addresses its own 8-B slot; HW treats the
// group's 128 B as a row-major 4x16 (vox x bin) tile and lane c receives
// COLUMN c (4 elems). This round re-lays the image for that model:
//   image = 2 bin-regions (L: bins 0..15, H: 16..31) x 16 dense 128-B tiles;
//   tile q = voxels 4q..4q+3, [voxel][bin] row-major.
//   Writes: lane=voxel, 3x ds_write_b128 at 32*lane (+0,+16,+2048);
//           bins 24..31 never written (pollute only unread C rows/cols;
//           C[i][j] sums only its own row/col products - no mixing).
//   Reads:  slot addr (g&1)*2048+(g>>1)*256+(l&15)*8, offsets s*512(+128)
//           -> lane (m,h) gets bin m, voxels 16s+8h+{0..7}: fragments
//           bit-identical to the validated scatter kernel's.
// Ops/chunk/wave: 29 -> 22, no zeroing, no data-dependent conflicts.
// Downstream: round-11 proven two-kernel structure unchanged.

#define NBINS   23
#define NCELLS  529
#define NBATCH  4
#define NVOX    884736
#define PBLK    432               // K1 blocks per batch: 432 * 2048 = 884736
#define RPB     16                // partial rows per reduce block (432/27)
#define RBLK    (PBLK / RPB)      // 27
#define RTOT    (RBLK * NBATCH)   // 108 reduce blocks total
#define IMGB3   4096              // 2 regions x 16 tiles x 128 B
#define WREG    (2 * IMGB3)       // 8192 B per wave (A + B images)
#define SMEMB   (4 * WREG)        // 32768 B -> 5 blocks/CU

typedef float    vf4  __attribute__((ext_vector_type(4)));
typedef _Float16 h4   __attribute__((ext_vector_type(4)));
typedef _Float16 h8   __attribute__((ext_vector_type(8)));
typedef float    f16v __attribute__((ext_vector_type(16)));

#define G1 0.13533528f        // exp(-2)
#define G2 3.3546263e-4f      // exp(-8)
#define G3 1.5229979e-8f      // exp(-18)

// 16-bin window at bins i0..i0+15, i0 in {0,8,16}. Per-quad factorization:
// quad q at base bq=i0+4q: vq = x - bq/22, W0=exp(-968 vq^2), R=exp(88 vq),
// w[4q+t] = W0*R^t*G(t) via sequential p*=R (no intermediate overflow; far
// quads underflow W0 to exact 0 = correct). Sum masks bins >= 23 by i0-case.
__device__ __forceinline__ float window16(float x, int& i0, float* w)
{
    x = fminf(fmaxf(x, 0.0f), 1.0f);
    int ka = (int)floorf(fmaf(x, 22.0f, 0.5f));
    i0 = (ka >= 11) ? ((ka >= 19) ? 16 : 8) : 0;
    #pragma unroll
    for (int q = 0; q < 4; ++q) {
        float vq = fmaf((float)(i0 + 4 * q), -(1.0f / 22.0f), x);
        float W0 = __expf(-968.0f * vq * vq);
        float R  = __expf(88.0f * vq);
        float p  = W0;
        w[4 * q + 0] = p;
        p *= R;  w[4 * q + 1] = p * G1;
        p *= R;  w[4 * q + 2] = p * G2;
        p *= R;  w[4 * q + 3] = p * G3;
    }
    float s06  = ((w[0] + w[1]) + (w[2] + w[3])) + ((w[4] + w[5]) + w[6]);
    float s714 = ((w[7] + w[8]) + (w[9] + w[10]))
               + ((w[11] + w[12]) + (w[13] + w[14]));
    float s = s06;
    if (i0 < 16)  s += s714;      // i0=16: bins 23..31 invalid beyond t=6
    if (i0 == 0)  s += w[15];     // i0=8: t=15 is bin 23 (invalid)
    return s;
}

// Write one voxel's 24 real bins as 3 ds_write_b128 into the tiled layout.
// (vox v, bin B) byte addr: region (B>>4)*2048 + tile (v>>2)*128
//                           + row (v&3)*32 + (B&15)*2;  base = 32*v.
__device__ __forceinline__ void write_col3(char* img, int lane, const float* w,
                                           float scale, int i0)
{
    h8 lo, hi;
    #pragma unroll
    for (int t = 0; t < 8; ++t) {
        lo[t] = (_Float16)(w[t] * scale);
        hi[t] = (_Float16)(w[t + 8] * scale);
    }
    h8 z = {};
    h8 c0 = (i0 == 0)  ? lo : z;                          // bins 0..7
    h8 c1 = (i0 == 0)  ? hi : ((i0 == 8) ? lo : z);       // bins 8..15
    h8 c2 = (i0 == 16) ? lo : ((i0 == 8) ? hi : z);       // bins 16..23
    const int aw = lane * 32;
    *(h8*)(img + aw)        = c0;
    *(h8*)(img + aw + 16)   = c1;
    *(h8*)(img + aw + 2048) = c2;
}

// ---------------- K1: fused Parzen-window + MFMA joint histogram ----------------
__global__ __launch_bounds__(256, 5)
void mi_mfma(const float* __restrict__ pred,
             const float* __restrict__ targ,
             float* __restrict__ partial,      // [NBATCH*PBLK][NCELLS]
             double* __restrict__ pab64,       // zeroed here for K2
             int* __restrict__ counter)
{
    __shared__ __align__(16) char smem[SMEMB];

    if (blockIdx.x == 0 && blockIdx.y == 0) {
        for (int c = threadIdx.x; c < NBATCH * NCELLS; c += 256)
            pab64[c] = 0.0;
        if (threadIdx.x == 0) *counter = 0;
    }

    const int p    = blockIdx.x;
    const int b    = blockIdx.y;
    const int wv   = threadIdx.x >> 6;
    const int lane = threadIdx.x & 63;
    const int m    = lane & 31;               // C-column lane index (epilogue)
    const int h    = lane >> 5;               // k-half selector (epilogue)

    char* wbase = smem + wv * WREG;
    char* Aimg  = wbase;
    char* Bimg  = wbase + IMGB3;

    const size_t base = (size_t)b * NVOX + (size_t)p * 2048 + (size_t)wv * 512
                      + (size_t)lane * 8;
    const vf4* __restrict__ px4 = (const vf4*)(pred + base);
    const vf4* __restrict__ py4 = (const vf4*)(targ + base);
    vf4 xa = px4[0], xb = px4[1], ya = py4[0], yb = py4[1];
    float xs[8] = {xa.x, xa.y, xa.z, xa.w, xb.x, xb.y, xb.z, xb.w};
    float ys[8] = {ya.x, ya.y, ya.z, ya.w, yb.x, yb.y, yb.z, yb.w};

    // tr slot address (chunk-invariant): group g = lane>>4 reads
    // region (g&1), voxel-quad pair (g>>1); lane&15 selects its 8-B slot.
    // (generic LDS ptr low-32 == DS byte address: LLVM builds the generic
    // as [lo = LDS offset, hi = aperture].)
    const int g = lane >> 4;
    const uint32_t aA = (uint32_t)(uintptr_t)Aimg
                      + (uint32_t)((g & 1) * 2048 + (g >> 1) * 256
                                   + (lane & 15) * 8);
    const uint32_t aB = aA + IMGB3;

    f16v acc = {};

    #pragma unroll
    for (int c = 0; c < 8; ++c) {
        int iA, iB;
        float wA[16], wB[16];
        float sa = window16(xs[c], iA, wA);
        float sb = window16(ys[c], iB, wB);
        float inv = __builtin_amdgcn_rcpf(sa * sb);   // fold both norms onto A

        write_col3(Aimg, lane, wA, inv,  iA);
        write_col3(Bimg, lane, wB, 1.0f, iB);

        // retire the 6 ds_write_b128 before the tr reads consume the tiles
        asm volatile("s_waitcnt lgkmcnt(0)" ::: "memory");
        __builtin_amdgcn_sched_barrier(0);

        // 4 k-steps of 32x32x16 (K=16 voxels each). Each tr read delivers
        // lane (m,h): bin m of 4 consecutive voxels; al: 16s+8h+0..3,
        // ah: +4..7 (offset +128 = next tile).
        #pragma unroll
        for (int s = 0; s < 4; ++s) {
            h4 al, ah, bl, bh;
            asm volatile("ds_read_b64_tr_b16 %0, %1 offset:%c2"
                         : "=v"(al) : "v"(aA), "i"(s * 512) : "memory");
            asm volatile("ds_read_b64_tr_b16 %0, %1 offset:%c2"
                         : "=v"(ah) : "v"(aA), "i"(s * 512 + 128) : "memory");
            asm volatile("ds_read_b64_tr_b16 %0, %1 offset:%c2"
                         : "=v"(bl) : "v"(aB), "i"(s * 512) : "memory");
            asm volatile("ds_read_b64_tr_b16 %0, %1 offset:%c2"
                         : "=v"(bh) : "v"(aB), "i"(s * 512 + 128) : "memory");
            asm volatile("s_waitcnt lgkmcnt(0)" ::: "memory");
            __builtin_amdgcn_sched_barrier(0);       // rule #18
            h8 Af = __builtin_shufflevector(al, ah, 0, 1, 2, 3, 4, 5, 6, 7);
            h8 Bf = __builtin_shufflevector(bl, bh, 0, 1, 2, 3, 4, 5, 6, 7);
            acc = __builtin_amdgcn_mfma_f32_32x32x16_f16(Af, Bf, acc, 0, 0, 0);
        }
    }

    // epilogue: C layout col=lane&31, row=(reg&3)+8*(reg>>2)+4*h (m74/m101)
    float* tile = (float*)wbase;               // reuse wave region
    #pragma unroll
    for (int r = 0; r < 16; ++r) {
        int row = (r & 3) + 8 * (r >> 2) + 4 * h;
        tile[row * 33 + m] = acc[r];
    }
    __syncthreads();
    for (int c = threadIdx.x; c < NCELLS; c += 256) {
        int i = c / NBINS, j = c % NBINS;
        float s = 0.0f;
        #pragma unroll
        for (int w = 0; w < 4; ++w)
            s += ((const float*)(smem + w * WREG))[i * 33 + j];
        partial[((size_t)(b * PBLK + p)) * NCELLS + c] = s;   // coalesced rows
    }
}

// ---- K2: coalesced fp64 reduction (27x4 blocks) + last-block MI finalize ----
__global__ __launch_bounds__(256)
void mi_reduce_final(const float* __restrict__ partial,
                     double* __restrict__ pab64,
                     int* __restrict__ counter,
                     float* __restrict__ out)
{
    __shared__ double s_pab[NCELLS];
    __shared__ double s_pa[NBINS];
    __shared__ double s_pb[NBINS];
    __shared__ double s_red[4];
    __shared__ int s_last;

    const int g = blockIdx.x;                 // 0..RBLK-1
    const int b = blockIdx.y;
    const int t = threadIdx.x;
    const float* __restrict__ src =
        partial + ((size_t)b * PBLK + (size_t)g * RPB) * NCELLS;

    double a0 = 0.0, a1 = 0.0, a2 = 0.0;
    #pragma unroll
    for (int p = 0; p < RPB; ++p) {
        const float* __restrict__ row = src + (size_t)p * NCELLS;
        a0 += (double)row[t];
        a1 += (double)row[256 + t];
        if (t < NCELLS - 512) a2 += (double)row[512 + t];
    }
    atomicAdd(&pab64[b * NCELLS + t],       a0);   // 27-way contention: cheap
    atomicAdd(&pab64[b * NCELLS + 256 + t], a1);
    if (t < NCELLS - 512) atomicAdd(&pab64[b * NCELLS + 512 + t], a2);

    __syncthreads();
    if (t == 0) {
        __threadfence();
        s_last = (atomicAdd(counter, 1) == RTOT - 1);
    }
    __syncthreads();
    if (!s_last) return;

    double total = 0.0;
    for (int bb = 0; bb < NBATCH; ++bb) {
        for (int c = t; c < NCELLS; c += 256)
            s_pab[c] = __hip_atomic_load(&pab64[bb * NCELLS + c],
                                         __ATOMIC_RELAXED,
                                         __HIP_MEMORY_SCOPE_AGENT)
                       * (1.0 / (double)NVOX);
        __syncthreads();
        if (t < NBINS) {
            double r = 0.0, cl = 0.0;
            for (int j = 0; j < NBINS; ++j) {
                r  += s_pab[t * NBINS + j];
                cl += s_pab[j * NBINS + t];
            }
            s_pa[t] = r; s_pb[t] = cl;
        }
        __syncthreads();
        double tt = 0.0;
        for (int c = t; c < NCELLS; c += 256) {
            double pv   = s_pab[c];
            double papb = s_pa[c / NBINS] * s_pb[c % NBINS];
            tt += pv * log((pv + 1e-7) / (papb + 1e-7) + 1e-7);
        }
        #pragma unroll
        for (int off = 32; off > 0; off >>= 1) tt += __shfl_down(tt, off, 64);
        if ((t & 63) == 0) s_red[t >> 6] = tt;
        __syncthreads();
        if (t == 0) total += s_red[0] + s_red[1] + s_red[2] + s_red[3];
        __syncthreads();
    }
    if (t == 0) out[0] = (float)(-total * 0.25);
}

extern "C" void kernel_launch(void* const* d_in, const int* in_sizes, int n_in,
                              void* d_out, int out_size, void* d_ws, size_t ws_size,
                              hipStream_t stream)
{
    const float* pred = (const float*)d_in[0];
    const float* targ = (const float*)d_in[1];
    float* out = (float*)d_out;
    char* ws = (char*)d_ws;

    // layout: [partial: NBATCH*PBLK*NCELLS f32 = 3.66 MB][pab64: 2116 f64][cnt]
    const size_t off_pab64 =
        ((size_t)NBATCH * PBLK * NCELLS * 4 + 255) & ~(size_t)255;

    float*  partial = (float*)ws;
    double* pab64   = (double*)(ws + off_pab64);
    int*    counter = (int*)(ws + off_pab64 + NBATCH * NCELLS * sizeof(double));

    mi_mfma<<<dim3(PBLK, NBATCH), 256, 0, stream>>>(pred, targ, partial,
                                                    pab64, counter);
    mi_reduce_final<<<dim3(RBLK, NBATCH), 256, 0, stream>>>(partial, pab64,
                                                            counter, out);
}

// Round 10
// 111.998 us; speedup vs baseline: 1.5729x; 1.0247x over previous
//
#include <hip/hip_runtime.h>
#include <math.h>

// MutualInformationLoss on MI355X — round 18.
// Round-17 (batched 16 tr reads + VALU inside the issue->drain window) gave
// NaN: with 16 in-flight asm destinations (32 VGPR) live across ~130 VALU
// instrs, any allocator-inserted copy/spill of a destination BEFORE the
// s_waitcnt reads an undefined register (compiler models asm outputs as
// immediately ready). Round 16 (4 live, empty drain window) passed.
// This round = round 16 + two risk-free schedule fixes:
//   1) waits 5->3/chunk: two read batches of 8 ("=&v" early-clobber, NOTHING
//      scheduled between issue and drain -> no spill insertion points).
//   2) window16(c+1) shadow between write-issue and write-drain (ds_writes
//      have no output regs -> zero spill risk; ~320cy VALU hides write lat).
// Downstream: proven round-11 two-kernel structure, unchanged.

#define NBINS   23
#define NCELLS  529
#define NBATCH  4
#define NVOX    884736
#define PBLK    432               // K1 blocks per batch: 432 * 2048 = 884736
#define RPB     16                // partial rows per reduce block (432/27)
#define RBLK    (PBLK / RPB)      // 27
#define RTOT    (RBLK * NBATCH)   // 108 reduce blocks total
#define IMGB3   4096              // 2 bin-regions x 16 tiles x 128 B
#define WREG    (2 * IMGB3)       // 8192 B per wave (A + B images)
#define SMEMB   (4 * WREG)        // 32768 B -> 5 blocks/CU

typedef float    vf4  __attribute__((ext_vector_type(4)));
typedef _Float16 h4   __attribute__((ext_vector_type(4)));
typedef _Float16 h8   __attribute__((ext_vector_type(8)));
typedef float    f16v __attribute__((ext_vector_type(16)));

#define G1 0.13533528f        // exp(-2)
#define G2 3.3546263e-4f      // exp(-8)
#define G3 1.5229979e-8f      // exp(-18)

// 16-bin window at bins i0..i0+15, i0 in {0,8,16}. Per-quad factorization:
// quad q at base bq=i0+4q: vq = x - bq/22, W0=exp(-968 vq^2), R=exp(88 vq),
// w[4q+t] = W0*R^t*G(t) via sequential p*=R (no intermediate overflow; far
// quads underflow W0 to exact 0 = correct). Sum masks bins >= 23 by i0-case.
__device__ __forceinline__ float window16(float x, int& i0, float* w)
{
    x = fminf(fmaxf(x, 0.0f), 1.0f);
    int ka = (int)floorf(fmaf(x, 22.0f, 0.5f));
    i0 = (ka >= 11) ? ((ka >= 19) ? 16 : 8) : 0;
    #pragma unroll
    for (int q = 0; q < 4; ++q) {
        float vq = fmaf((float)(i0 + 4 * q), -(1.0f / 22.0f), x);
        float W0 = __expf(-968.0f * vq * vq);
        float R  = __expf(88.0f * vq);
        float p  = W0;
        w[4 * q + 0] = p;
        p *= R;  w[4 * q + 1] = p * G1;
        p *= R;  w[4 * q + 2] = p * G2;
        p *= R;  w[4 * q + 3] = p * G3;
    }
    float s06  = ((w[0] + w[1]) + (w[2] + w[3])) + ((w[4] + w[5]) + w[6]);
    float s714 = ((w[7] + w[8]) + (w[9] + w[10]))
               + ((w[11] + w[12]) + (w[13] + w[14]));
    float s = s06;
    if (i0 < 16)  s += s714;      // i0=16: bins 23..31 invalid beyond t=6
    if (i0 == 0)  s += w[15];     // i0=8: t=15 is bin 23 (invalid)
    return s;
}

// Write one voxel's 24 real bins as 3 ds_write_b128 into the tiled layout.
// (vox v, bin B) byte addr: region (B>>4)*2048 + tile (v>>2)*128
//                           + row (v&3)*32 + (B&15)*2;  base = 32*v.
__device__ __forceinline__ void write_col3(char* img, int lane, const float* w,
                                           float scale, int i0)
{
    h8 lo, hi;
    #pragma unroll
    for (int t = 0; t < 8; ++t) {
        lo[t] = (_Float16)(w[t] * scale);
        hi[t] = (_Float16)(w[t + 8] * scale);
    }
    h8 z = {};
    h8 c0 = (i0 == 0)  ? lo : z;                          // bins 0..7
    h8 c1 = (i0 == 0)  ? hi : ((i0 == 8) ? lo : z);       // bins 8..15
    h8 c2 = (i0 == 16) ? lo : ((i0 == 8) ? hi : z);       // bins 16..23
    const int aw = lane * 32;
    *(h8*)(img + aw)        = c0;
    *(h8*)(img + aw + 16)   = c1;
    *(h8*)(img + aw + 2048) = c2;
}

// ---------------- K1: fused Parzen-window + MFMA joint histogram ----------------
__global__ __launch_bounds__(256, 5)
void mi_mfma(const float* __restrict__ pred,
             const float* __restrict__ targ,
             float* __restrict__ partial,      // [NBATCH*PBLK][NCELLS]
             double* __restrict__ pab64,       // zeroed here for K2
             int* __restrict__ counter)
{
    __shared__ __align__(16) char smem[SMEMB];

    if (blockIdx.x == 0 && blockIdx.y == 0) {
        for (int c = threadIdx.x; c < NBATCH * NCELLS; c += 256)
            pab64[c] = 0.0;
        if (threadIdx.x == 0) *counter = 0;
    }

    const int p    = blockIdx.x;
    const int b    = blockIdx.y;
    const int wv   = threadIdx.x >> 6;
    const int lane = threadIdx.x & 63;
    const int m    = lane & 31;               // C-column lane index (epilogue)
    const int h    = lane >> 5;               // k-half selector (epilogue)

    char* wbase = smem + wv * WREG;
    char* Aimg  = wbase;
    char* Bimg  = wbase + IMGB3;

    const size_t base = (size_t)b * NVOX + (size_t)p * 2048 + (size_t)wv * 512
                      + (size_t)lane * 8;
    const vf4* __restrict__ px4 = (const vf4*)(pred + base);
    const vf4* __restrict__ py4 = (const vf4*)(targ + base);
    vf4 xa = px4[0], xb = px4[1], ya = py4[0], yb = py4[1];
    float xs[8] = {xa.x, xa.y, xa.z, xa.w, xb.x, xb.y, xb.z, xb.w};
    float ys[8] = {ya.x, ya.y, ya.z, ya.w, yb.x, yb.y, yb.z, yb.w};

    // tr slot address (chunk-invariant): group g = lane>>4 reads region
    // (g&1), voxel-quad pair (g>>1); lane&15 selects its 8-B slot.
    const int g = lane >> 4;
    const uint32_t aA = (uint32_t)(uintptr_t)Aimg
                      + (uint32_t)((g & 1) * 2048 + (g >> 1) * 256
                                   + (lane & 15) * 8);
    const uint32_t aB = aA + IMGB3;

    f16v acc = {};

    // software pipeline: chunk-c windows precomputed in chunk c-1's WRITE
    // latency shadow (ds_writes have no dest regs -> no spill hazard).
    int iA, iB;
    float wA[16], wB[16];
    float sa  = window16(xs[0], iA, wA);
    float sb  = window16(ys[0], iB, wB);
    float inv = __builtin_amdgcn_rcpf(sa * sb);   // fold both norms onto A

    #pragma unroll
    for (int c = 0; c < 8; ++c) {
        write_col3(Aimg, lane, wA, inv,  iA);
        write_col3(Bimg, lane, wB, 1.0f, iB);

        // next chunk's window VALU in the write-latency shadow (SSA: the
        // h8 write sources were already converted from the old wA/wB).
        if (c < 7) {
            sa  = window16(xs[c + 1], iA, wA);
            sb  = window16(ys[c + 1], iB, wB);
            inv = __builtin_amdgcn_rcpf(sa * sb);
        }

        // write drain (volatile-asm ordering keeps the tr reads below)
        asm volatile("s_waitcnt lgkmcnt(0)" ::: "memory");

        // ---- batch 1: k-steps 0,1 (8 reads, nothing inside the window) ----
        h4 r0, r1, r2, r3, r4, r5, r6, r7;
        asm volatile("ds_read_b64_tr_b16 %0, %1 offset:0"    : "=&v"(r0) : "v"(aA) : "memory");
        asm volatile("ds_read_b64_tr_b16 %0, %1 offset:128"  : "=&v"(r1) : "v"(aA) : "memory");
        asm volatile("ds_read_b64_tr_b16 %0, %1 offset:0"    : "=&v"(r2) : "v"(aB) : "memory");
        asm volatile("ds_read_b64_tr_b16 %0, %1 offset:128"  : "=&v"(r3) : "v"(aB) : "memory");
        asm volatile("ds_read_b64_tr_b16 %0, %1 offset:512"  : "=&v"(r4) : "v"(aA) : "memory");
        asm volatile("ds_read_b64_tr_b16 %0, %1 offset:640"  : "=&v"(r5) : "v"(aA) : "memory");
        asm volatile("ds_read_b64_tr_b16 %0, %1 offset:512"  : "=&v"(r6) : "v"(aB) : "memory");
        asm volatile("ds_read_b64_tr_b16 %0, %1 offset:640"  : "=&v"(r7) : "v"(aB) : "memory");
        asm volatile("s_waitcnt lgkmcnt(0)" ::: "memory");
        __builtin_amdgcn_sched_barrier(0);       // rule 18
        acc = __builtin_amdgcn_mfma_f32_32x32x16_f16(
                  __builtin_shufflevector(r0, r1, 0,1,2,3,4,5,6,7),
                  __builtin_shufflevector(r2, r3, 0,1,2,3,4,5,6,7),
                  acc, 0, 0, 0);
        acc = __builtin_amdgcn_mfma_f32_32x32x16_f16(
                  __builtin_shufflevector(r4, r5, 0,1,2,3,4,5,6,7),
                  __builtin_shufflevector(r6, r7, 0,1,2,3,4,5,6,7),
                  acc, 0, 0, 0);

        // ---- batch 2: k-steps 2,3 ----
        h4 r8, r9, r10, r11, r12, r13, r14, r15;
        asm volatile("ds_read_b64_tr_b16 %0, %1 offset:1024" : "=&v"(r8)  : "v"(aA) : "memory");
        asm volatile("ds_read_b64_tr_b16 %0, %1 offset:1152" : "=&v"(r9)  : "v"(aA) : "memory");
        asm volatile("ds_read_b64_tr_b16 %0, %1 offset:1024" : "=&v"(r10) : "v"(aB) : "memory");
        asm volatile("ds_read_b64_tr_b16 %0, %1 offset:1152" : "=&v"(r11) : "v"(aB) : "memory");
        asm volatile("ds_read_b64_tr_b16 %0, %1 offset:1536" : "=&v"(r12) : "v"(aA) : "memory");
        asm volatile("ds_read_b64_tr_b16 %0, %1 offset:1664" : "=&v"(r13) : "v"(aA) : "memory");
        asm volatile("ds_read_b64_tr_b16 %0, %1 offset:1536" : "=&v"(r14) : "v"(aB) : "memory");
        asm volatile("ds_read_b64_tr_b16 %0, %1 offset:1664" : "=&v"(r15) : "v"(aB) : "memory");
        asm volatile("s_waitcnt lgkmcnt(0)" ::: "memory");
        __builtin_amdgcn_sched_barrier(0);       // rule 18
        acc = __builtin_amdgcn_mfma_f32_32x32x16_f16(
                  __builtin_shufflevector(r8,  r9,  0,1,2,3,4,5,6,7),
                  __builtin_shufflevector(r10, r11, 0,1,2,3,4,5,6,7),
                  acc, 0, 0, 0);
        acc = __builtin_amdgcn_mfma_f32_32x32x16_f16(
                  __builtin_shufflevector(r12, r13, 0,1,2,3,4,5,6,7),
                  __builtin_shufflevector(r14, r15, 0,1,2,3,4,5,6,7),
                  acc, 0, 0, 0);
    }

    // epilogue: C layout col=lane&31, row=(reg&3)+8*(reg>>2)+4*h (m74/m101)
    float* tile = (float*)wbase;               // reuse wave region
    #pragma unroll
    for (int r = 0; r < 16; ++r) {
        int row = (r & 3) + 8 * (r >> 2) + 4 * h;
        tile[row * 33 + m] = acc[r];
    }
    __syncthreads();
    for (int c = threadIdx.x; c < NCELLS; c += 256) {
        int i = c / NBINS, j = c % NBINS;
        float s = 0.0f;
        #pragma unroll
        for (int w = 0; w < 4; ++w)
            s += ((const float*)(smem + w * WREG))[i * 33 + j];
        partial[((size_t)(b * PBLK + p)) * NCELLS + c] = s;   // coalesced rows
    }
}

// ---- K2: coalesced fp64 reduction (27x4 blocks) + last-block MI finalize ----
__global__ __launch_bounds__(256)
void mi_reduce_final(const float* __restrict__ partial,
                     double* __restrict__ pab64,
                     int* __restrict__ counter,
                     float* __restrict__ out)
{
    __shared__ double s_pab[NCELLS];
    __shared__ double s_pa[NBINS];
    __shared__ double s_pb[NBINS];
    __shared__ double s_red[4];
    __shared__ int s_last;

    const int g = blockIdx.x;                 // 0..RBLK-1
    const int b = blockIdx.y;
    const int t = threadIdx.x;
    const float* __restrict__ src =
        partial + ((size_t)b * PBLK + (size_t)g * RPB) * NCELLS;

    double a0 = 0.0, a1 = 0.0, a2 = 0.0;
    #pragma unroll
    for (int p = 0; p < RPB; ++p) {
        const float* __restrict__ row = src + (size_t)p * NCELLS;
        a0 += (double)row[t];
        a1 += (double)row[256 + t];
        if (t < NCELLS - 512) a2 += (double)row[512 + t];
    }
    atomicAdd(&pab64[b * NCELLS + t],       a0);   // 27-way contention: cheap
    atomicAdd(&pab64[b * NCELLS + 256 + t], a1);
    if (t < NCELLS - 512) atomicAdd(&pab64[b * NCELLS + 512 + t], a2);

    __syncthreads();
    if (t == 0) {
        __threadfence();
        s_last = (atomicAdd(counter, 1) == RTOT - 1);
    }
    __syncthreads();
    if (!s_last) return;

    double total = 0.0;
    for (int bb = 0; bb < NBATCH; ++bb) {
        for (int c = t; c < NCELLS; c += 256)
            s_pab[c] = __hip_atomic_load(&pab64[bb * NCELLS + c],
                                         __ATOMIC_RELAXED,
                                         __HIP_MEMORY_SCOPE_AGENT)
                       * (1.0 / (double)NVOX);
        __syncthreads();
        if (t < NBINS) {
            double r = 0.0, cl = 0.0;
            for (int j = 0; j < NBINS; ++j) {
                r  += s_pab[t * NBINS + j];
                cl += s_pab[j * NBINS + t];
            }
            s_pa[t] = r; s_pb[t] = cl;
        }
        __syncthreads();
        double tt = 0.0;
        for (int c = t; c < NCELLS; c += 256) {
            double pv   = s_pab[c];
            double papb = s_pa[c / NBINS] * s_pb[c % NBINS];
            tt += pv * log((pv + 1e-7) / (papb + 1e-7) + 1e-7);
        }
        #pragma unroll
        for (int off = 32; off > 0; off >>= 1) tt += __shfl_down(tt, off, 64);
        if ((t & 63) == 0) s_red[t >> 6] = tt;
        __syncthreads();
        if (t == 0) total += s_red[0] + s_red[1] + s_red[2] + s_red[3];
        __syncthreads();
    }
    if (t == 0) out[0] = (float)(-total * 0.25);
}

extern "C" void kernel_launch(void* const* d_in, const int* in_sizes, int n_in,
                              void* d_out, int out_size, void* d_ws, size_t ws_size,
                              hipStream_t stream)
{
    const float* pred = (const float*)d_in[0];
    const float* targ = (const float*)d_in[1];
    float* out = (float*)d_out;
    char* ws = (char*)d_ws;

    // layout: [partial: NBATCH*PBLK*NCELLS f32 = 3.66 MB][pab64: 2116 f64][cnt]
    const size_t off_pab64 =
        ((size_t)NBATCH * PBLK * NCELLS * 4 + 255) & ~(size_t)255;

    float*  partial = (float*)ws;
    double* pab64   = (double*)(ws + off_pab64);
    int*    counter = (int*)(ws + off_pab64 + NBATCH * NCELLS * sizeof(double));

    mi_mfma<<<dim3(PBLK, NBATCH), 256, 0, stream>>>(pred, targ, partial,
                                                    pab64, counter);
    mi_reduce_final<<<dim3(RBLK, NBATCH), 256, 0, stream>>>(partial, pab64,
                                                            counter, out);
}

// Round 11
// 99.745 us; speedup vs baseline: 1.7662x; 1.1228x over previous
//
#include <hip/hip_runtime.h>
#include <math.h>

// MutualInformationLoss on MI355X — round 19.
// Round-18 post-mortem: tr-tiled K1 stuck at ~46us vs scatter's ~42.9 (drain
// structure serializes the wave; closing it re-enters the r17 spill-NaN
// regime). tr path CLOSED. K1 restored to the round-11 scatter kernel
// (107.2us best) byte-for-byte.
// This round attacks the ~21us downstream: the single-block finalize made
// 2116 device-scope atomic loads in 4 serial phases + 2116 fp64 logs while
// the GPU idled. Now:
//   - per-batch ticket cnt[b]: last of each batch's 27 K2 blocks finalizes
//     THAT batch (529 loads, concurrent across 4 blocks);
//   - grand ticket cnt[4]: last finalizer sums the 4 stored mi_b doubles in
//     fixed order (deterministic) and writes out[0].
// All coherence stays in the proven O(100)-block regime (round-13 lesson:
// device-scope machinery is fatal only at O(1000) blocks).

#define NBINS   23
#define NCELLS  529
#define NBATCH  4
#define NVOX    884736
#define PBLK    432               // K1 blocks per batch: 432 * 2048 = 884736
#define RPB     16                // partial rows per reduce block (432/27)
#define RBLK    (PBLK / RPB)      // 27
#define RS      72                // image row stride in halves (144 B)
#define IMGB    (24 * RS * 2)     // 3456 B per image (rows 0..23)
#define WREG    (2 * IMGB)        // 6912 B per wave (A + B images)
#define SMEMB   (4 * WREG + 2048) // 29696 B: guard covers row 24..31 overreads

typedef float    vf4  __attribute__((ext_vector_type(4)));
typedef _Float16 h8   __attribute__((ext_vector_type(8)));
typedef float    f16v __attribute__((ext_vector_type(16)));

#define G1 0.13533528f        // exp(-2)
#define G2 3.3546263e-4f      // exp(-8)
#define G3 1.5229979e-8f      // exp(-18)

// 7-bin window at rows i0..i0+6 via factored Gaussian (2 exp + 1 rcp):
//   w(t) = W0 * R^t * G(t), W0=exp(-968 v^2), R=exp(88 v), v = x - c_mid
__device__ __forceinline__ float window7(float x, int& i0, float* w)
{
    x = fminf(fmaxf(x, 0.0f), 1.0f);
    int ka = (int)floorf(fmaf(x, 22.0f, 0.5f));
    i0 = min(max(ka - 3, 0), 16);
    float v  = fmaf((float)(i0 + 3), -(1.0f / 22.0f), x);
    float W0 = __expf(-968.0f * v * v);
    float R  = __expf(88.0f * v);
    float Ri = __builtin_amdgcn_rcpf(R);
    float R2 = R * R,   R3 = R2 * R;
    float R2i = Ri * Ri, R3i = R2i * Ri;
    w[0] = W0 * (R3i * G3);
    w[1] = W0 * (R2i * G2);
    w[2] = W0 * (Ri  * G1);
    w[3] = W0;
    w[4] = W0 * (R   * G1);
    w[5] = W0 * (R2  * G2);
    w[6] = W0 * (R3  * G3);
    return ((w[0] + w[6]) + (w[1] + w[5])) + ((w[2] + w[4]) + w[3]);
}

// ---------------- K1: fused Parzen-window + MFMA joint histogram ----------------
__global__ __launch_bounds__(256, 5)
void mi_mfma(const float* __restrict__ pred,
             const float* __restrict__ targ,
             float* __restrict__ partial,      // [NBATCH*PBLK][NCELLS]
             double* __restrict__ pab64,       // zeroed here for K2
             int* __restrict__ cnt)            // [5], zeroed here for K2
{
    __shared__ __align__(16) char smem[SMEMB];

    // Block (0,0) zeroes K2's accumulators + counters (replaces memset;
    // K2 runs after K1 completes in stream order, so no race).
    if (blockIdx.x == 0 && blockIdx.y == 0) {
        for (int c = threadIdx.x; c < NBATCH * NCELLS; c += 256)
            pab64[c] = 0.0;
        if (threadIdx.x < 5) cnt[threadIdx.x] = 0;
    }

    const int p    = blockIdx.x;
    const int b    = blockIdx.y;
    const int wv   = threadIdx.x >> 6;
    const int lane = threadIdx.x & 63;
    const int m    = lane & 31;               // bin row for fragment reads
    const int h    = lane >> 5;               // k-half selector

    char* wbase = smem + wv * WREG;
    _Float16* Aimg = (_Float16*)wbase;
    _Float16* Bimg = (_Float16*)(wbase + IMGB);

    const size_t base = (size_t)b * NVOX + (size_t)p * 2048 + (size_t)wv * 512
                      + (size_t)lane * 8;
    const vf4* __restrict__ px4 = (const vf4*)(pred + base);
    const vf4* __restrict__ py4 = (const vf4*)(targ + base);
    vf4 xa = px4[0], xb = px4[1], ya = py4[0], yb = py4[1];
    float xs[8] = {xa.x, xa.y, xa.z, xa.w, xb.x, xb.y, xb.z, xb.w};
    float ys[8] = {ya.x, ya.y, ya.z, ya.w, yb.x, yb.y, yb.z, yb.w};

    f16v acc = {};

    #pragma unroll
    for (int c = 0; c < 8; ++c) {
        // zero rows 0..23 of BOTH images in one contiguous 6912 B span.
        // Rows 24..31 never written; reads of them only pollute C rows/cols
        // >= 23, which are never consumed (validated round 9).
        vf4 z = {0.f, 0.f, 0.f, 0.f};
        #pragma unroll
        for (int it = 0; it < 6; ++it)
            *(vf4*)(wbase + (it * 64 + lane) * 16) = z;
        if (lane < 48)
            *(vf4*)(wbase + (384 + lane) * 16) = z;

        int ia, ja;
        float wa[7], wb[7];
        float sa = window7(xs[c], ia, wa);
        float sb = window7(ys[c], ja, wb);
        float inv = __builtin_amdgcn_rcpf(sa * sb);   // fold both norms onto A

        #pragma unroll
        for (int t = 0; t < 7; ++t) {
            Aimg[(ia + t) * RS + lane] = (_Float16)(wa[t] * inv);  // RNE cvt
            Bimg[(ja + t) * RS + lane] = (_Float16)wb[t];
        }

        // 4 k-steps of 32x32x16 (K=16 voxels each)
        #pragma unroll
        for (int s = 0; s < 4; ++s) {
            h8 Af = *(const h8*)(Aimg + m * RS + 16 * s + 8 * h);
            h8 Bf = *(const h8*)(Bimg + m * RS + 16 * s + 8 * h);
            acc = __builtin_amdgcn_mfma_f32_32x32x16_f16(Af, Bf, acc, 0, 0, 0);
        }
    }

    // epilogue: C layout col=lane&31, row=(reg&3)+8*(reg>>2)+4*h (m74/m101)
    float* tile = (float*)wbase;               // reuse wave region
    #pragma unroll
    for (int r = 0; r < 16; ++r) {
        int row = (r & 3) + 8 * (r >> 2) + 4 * h;
        tile[row * 33 + m] = acc[r];
    }
    __syncthreads();
    for (int c = threadIdx.x; c < NCELLS; c += 256) {
        int i = c / NBINS, j = c % NBINS;
        float s = 0.0f;
        #pragma unroll
        for (int w = 0; w < 4; ++w)
            s += ((const float*)(smem + w * WREG))[i * 33 + j];
        partial[((size_t)(b * PBLK + p)) * NCELLS + c] = s;   // coalesced rows
    }
}

// -- K2: fp64 reduction (27x4) + per-batch finalize + grand-final ticket --
__global__ __launch_bounds__(256)
void mi_reduce_batch(const float* __restrict__ partial,
                     double* __restrict__ pab64,
                     int* __restrict__ cnt,       // [5]
                     double* __restrict__ mi_s,   // [4]
                     float* __restrict__ out)
{
    __shared__ double s_pab[NCELLS];
    __shared__ double s_pa[NBINS];
    __shared__ double s_pb[NBINS];
    __shared__ double s_red[4];
    __shared__ int s_last;

    const int g = blockIdx.x;                 // 0..RBLK-1
    const int b = blockIdx.y;
    const int t = threadIdx.x;
    const float* __restrict__ src =
        partial + ((size_t)b * PBLK + (size_t)g * RPB) * NCELLS;

    double a0 = 0.0, a1 = 0.0, a2 = 0.0;
    #pragma unroll
    for (int p = 0; p < RPB; ++p) {
        const float* __restrict__ row = src + (size_t)p * NCELLS;
        a0 += (double)row[t];
        a1 += (double)row[256 + t];
        if (t < NCELLS - 512) a2 += (double)row[512 + t];
    }
    atomicAdd(&pab64[b * NCELLS + t],       a0);   // 27-way contention: cheap
    atomicAdd(&pab64[b * NCELLS + 256 + t], a1);
    if (t < NCELLS - 512) atomicAdd(&pab64[b * NCELLS + 512 + t], a2);

    // per-batch ticket: __syncthreads drains vmcnt (atomics committed),
    // release fence + counter bump; last block of THIS batch finalizes it.
    __syncthreads();
    if (t == 0) {
        __threadfence();
        s_last = (atomicAdd(&cnt[b], 1) == RBLK - 1);
    }
    __syncthreads();
    if (!s_last) return;

    // finalize batch b only (529 device-scope loads, one latency round;
    // the 4 batch-finalizers run concurrently on different CUs).
    for (int c = t; c < NCELLS; c += 256)
        s_pab[c] = __hip_atomic_load(&pab64[b * NCELLS + c],
                                     __ATOMIC_RELAXED,
                                     __HIP_MEMORY_SCOPE_AGENT)
                   * (1.0 / (double)NVOX);
    __syncthreads();
    if (t < NBINS) {
        double r = 0.0, cl = 0.0;
        for (int j = 0; j < NBINS; ++j) {
            r  += s_pab[t * NBINS + j];
            cl += s_pab[j * NBINS + t];
        }
        s_pa[t] = r; s_pb[t] = cl;
    }
    __syncthreads();
    double tt = 0.0;
    for (int c = t; c < NCELLS; c += 256) {
        double pv   = s_pab[c];
        double papb = s_pa[c / NBINS] * s_pb[c % NBINS];
        tt += pv * log((pv + 1e-7) / (papb + 1e-7) + 1e-7);
    }
    #pragma unroll
    for (int off = 32; off > 0; off >>= 1) tt += __shfl_down(tt, off, 64);
    if ((t & 63) == 0) s_red[t >> 6] = tt;
    __syncthreads();

    // grand-final ticket: last batch-finalizer sums the 4 mi values in
    // FIXED index order (deterministic) and writes out.
    if (t == 0) {
        double mi_b = s_red[0] + s_red[1] + s_red[2] + s_red[3];
        __hip_atomic_store(&mi_s[b], mi_b, __ATOMIC_RELEASE,
                           __HIP_MEMORY_SCOPE_AGENT);
        __threadfence();
        if (atomicAdd(&cnt[4], 1) == NBATCH - 1) {
            double m0 = __hip_atomic_load(&mi_s[0], __ATOMIC_RELAXED,
                                          __HIP_MEMORY_SCOPE_AGENT);
            double m1 = __hip_atomic_load(&mi_s[1], __ATOMIC_RELAXED,
                                          __HIP_MEMORY_SCOPE_AGENT);
            double m2 = __hip_atomic_load(&mi_s[2], __ATOMIC_RELAXED,
                                          __HIP_MEMORY_SCOPE_AGENT);
            double m3 = __hip_atomic_load(&mi_s[3], __ATOMIC_RELAXED,
                                          __HIP_MEMORY_SCOPE_AGENT);
            out[0] = (float)(-((m0 + m1) + (m2 + m3)) * 0.25);
        }
    }
}

extern "C" void kernel_launch(void* const* d_in, const int* in_sizes, int n_in,
                              void* d_out, int out_size, void* d_ws, size_t ws_size,
                              hipStream_t stream)
{
    const float* pred = (const float*)d_in[0];
    const float* targ = (const float*)d_in[1];
    float* out = (float*)d_out;
    char* ws = (char*)d_ws;

    // layout: [partial: NBATCH*PBLK*NCELLS f32 = 3.66 MB][pab64: 2116 f64]
    //         [cnt: 5 ints][pad][mi_s: 4 f64]
    const size_t off_pab64 =
        ((size_t)NBATCH * PBLK * NCELLS * 4 + 255) & ~(size_t)255;
    const size_t off_cnt = off_pab64 + (size_t)NBATCH * NCELLS * sizeof(double);
    const size_t off_mi  = (off_cnt + 5 * sizeof(int) + 7) & ~(size_t)7;

    float*  partial = (float*)ws;
    double* pab64   = (double*)(ws + off_pab64);
    int*    cnt     = (int*)(ws + off_cnt);
    double* mi_s    = (double*)(ws + off_mi);

    mi_mfma<<<dim3(PBLK, NBATCH), 256, 0, stream>>>(pred, targ, partial,
                                                    pab64, cnt);
    mi_reduce_batch<<<dim3(RBLK, NBATCH), 256, 0, stream>>>(partial, pab64,
                                                            cnt, mi_s, out);
}